// Round 3
// baseline (712.460 us; speedup 1.0000x reference)
//
#include <hip/hip_runtime.h>
#include <math.h>

// ws layout (floats):
//   esq   : [4096]
//   state : [2][64*8192]   ping-pong f_rest, [b][yx*32+c]
//   fhat  : [64*8192]      f_hat accumulator, [b][yx*32+c]
//   psc   : [2][64][4][256] float
//   pix   : [2][64][4][256] int
#define WS_ESQ   0
#define WS_STATE 4096
#define WS_FHAT  (4096 + 2*524288)
#define WS_PSC   (4096 + 3*524288)
#define WS_PIX   (4096 + 3*524288 + 2*65536)

// numpy pairwise sum of 32 floats (unroll-8 then tree), inputs pre-rounded
__device__ __forceinline__ float np_pairwise32(const float* sq) {
    float r[8];
    #pragma unroll
    for (int t = 0; t < 8; ++t) {
        float a = __fadd_rn(sq[t], sq[t+8]);
        a = __fadd_rn(a, sq[t+16]);
        r[t] = __fadd_rn(a, sq[t+24]);
    }
    float l = __fadd_rn(__fadd_rn(r[0], r[1]), __fadd_rn(r[2], r[3]));
    float h = __fadd_rn(__fadd_rn(r[4], r[5]), __fadd_rn(r[6], r[7]));
    return __fadd_rn(l, h);
}

__global__ void vq_prep(const float* __restrict__ emb, float* __restrict__ esq) {
    int j = blockIdx.x * 256 + threadIdx.x;
    if (j < 4096) {
        float sq[32];
        #pragma unroll
        for (int c = 0; c < 32; ++c) { float e = emb[j*32 + c]; sq[c] = __fmul_rn(e, e); }
        esq[j] = np_pairwise32(sq);
    }
}

__device__ __forceinline__ double keys64(double x) {
    // jax keys cubic (a=-0.5); x>=1 branch matches jnp.where(x>=1,...)
    if (x < 1.0)      return ((1.5*x - 2.5)*x)*x + 1.0;
    else if (x < 2.0) return ((-0.5*x + 2.5)*x - 4.0)*x + 2.0;
    return 0.0;
}

__global__ __launch_bounds__(1024) void vq_scale(
    const float* __restrict__ f, const float* __restrict__ emb,
    const float* __restrict__ esq, float* __restrict__ state,
    float* __restrict__ fhat, float* __restrict__ psc, int* __restrict__ pix,
    int sIdx, int pn, int pnPrev)
{
    __shared__ __align__(16) float frest[256*33]; // [yx*33+c]; overlaid by psc_l/pix_l in scan
    __shared__ float zh[5440];        // union: h [v*32+c] (P3-P5) / zT [c*VP+v] (P7-P9)
    __shared__ int   idx_arr[256];
    __shared__ float U[16*16];        // bicubic weights [out][in], fp64->fp32 like jax
    __shared__ float zsql[256];

    float* psc_l = frest;                 // scan-phase overlay: 16*64 floats
    int*   pix_l = (int*)(frest + 1024);  // 16*64 ints

    const int tid   = threadIdx.x;
    const int b     = blockIdx.x >> 2;
    const int chunk = blockIdx.x & 3;

    // ---- P1: load f_rest into LDS ----
    if (sIdx == 0) {
        for (int o = tid; o < 8192; o += 1024) {           // o = c*256+yx (coalesced in f)
            int c = o >> 8, yx = o & 255;
            frest[yx*33 + c] = f[b*8192 + o];
        }
    } else {
        const float* st = state + (size_t)(sIdx & 1)*524288 + b*8192;
        for (int o = tid; o < 8192; o += 1024)
            frest[(o >> 5)*33 + (o & 31)] = st[o];
    }
    __syncthreads();

    if (sIdx > 0) {
        const int Vp = pnPrev * pnPrev;
        const int ps = (sIdx - 1) & 1;
        // ---- P2: combine prev-scale partial argmins (ascending chunk = ascending j) ----
        if (tid < Vp) {
            float best = INFINITY; int bi = 0;
            for (int ch = 0; ch < 4; ++ch) {
                float sc = psc[(size_t)(ps*64 + b)*1024 + ch*256 + tid];
                if (sc < best) { best = sc; bi = pix[(size_t)(ps*64 + b)*1024 + ch*256 + tid]; }
            }
            idx_arr[tid] = bi;
        }
        __syncthreads();
        // ---- P3: gather h = emb[idx] ----
        for (int t = tid; t < Vp*32; t += 1024)
            zh[t] = emb[(size_t)idx_arr[t >> 5]*32 + (t & 31)];
        // ---- P4: bicubic weights in fp64 exactly like jax, cast fp32 after normalize ----
        if (tid < 16) {
            double scl = 16.0 / (double)pnPrev;          // RN64, as jax computes scale
            double inv = 1.0 / scl;                      // RN64 reciprocal
            double s = ((double)tid + 0.5) * inv - 0.5;
            double w64[16]; double tot = 0.0;
            for (int q = 0; q < pnPrev; ++q) {
                double wv = keys64(fabs(s - (double)q));
                w64[q] = wv; tot += wv;
            }
            for (int q = 0; q < pnPrev; ++q) U[tid*16 + q] = (float)(w64[q] / tot);
        }
        __syncthreads();
        // ---- P5: upsample-apply (np einsum order: term=((h*wy)*wx), p outer, q inner,
        //          separate mul/add roundings), subtract, persist state & fhat ----
        float* stn = state + (size_t)((sIdx + 1) & 1)*524288 + b*8192;
        float* fh  = fhat + (size_t)b*8192;
        for (int o = tid; o < 8192; o += 1024) {
            int c = o & 31, yx = o >> 5, y = yx >> 4, x = yx & 15;
            float acc = 0.f;
            for (int p = 0; p < pnPrev; ++p) {
                float wy = U[y*16 + p];
                for (int q = 0; q < pnPrev; ++q) {
                    float t0 = __fmul_rn(zh[(p*pnPrev + q)*32 + c], wy);
                    t0 = __fmul_rn(t0, U[x*16 + q]);
                    acc = __fadd_rn(acc, t0);
                }
            }
            float fr = __fsub_rn(frest[yx*33 + c], acc);
            frest[yx*33 + c] = fr;
            if (chunk == 0) {
                stn[o] = fr;
                fh[o] = (sIdx == 1) ? acc : __fadd_rn(fh[o], acc);  // f_hat = f_hat + h chain
            }
        }
        __syncthreads();
    } else {
        // s==0: persist unmodified f_rest to next slot
        float* stn = state + (size_t)1*524288 + b*8192;
        if (chunk == 0)
            for (int o = tid; o < 8192; o += 1024)
                stn[o] = frest[(o >> 5)*33 + (o & 31)];
    }

    // ---- P7: area pooling, np einsum order: term=((Mh*Mw)*f), h outer, w inner ----
    const int V  = pn * pn;
    const int VP = V | 1;
    if (pn < 16) {
        for (int t = tid; t < V*32; t += 1024) {
            int v = t >> 5, c = t & 31;
            int p = v / pn, q = v - p*pn;
            int sh = (p*16)/pn, eh = ((p+1)*16 + pn - 1)/pn;
            int sw = (q*16)/pn, ew = ((q+1)*16 + pn - 1)/pn;
            float Mh = (float)(1.0/(double)(eh - sh));   // np float(1.0/w) -> fp32 store
            float Mw = (float)(1.0/(double)(ew - sw));
            float coef = __fmul_rn(Mh, Mw);
            float acc = 0.f;
            for (int hh = sh; hh < eh; ++hh)
                for (int wy = sw; wy < ew; ++wy)
                    acc = __fadd_rn(acc, __fmul_rn(coef, frest[(hh*16 + wy)*33 + c]));
            zh[c*VP + v] = acc;
        }
    }
    __syncthreads();

    // ---- P8: zsq per vector, numpy pairwise-32 of rounded squares ----
    if (tid < V) {
        float sq[32];
        if (pn == 16) {
            #pragma unroll
            for (int c = 0; c < 32; ++c) { float z = frest[tid*33 + c]; sq[c] = __fmul_rn(z, z); }
        } else {
            #pragma unroll
            for (int c = 0; c < 32; ++c) { float z = zh[c*VP + tid]; sq[c] = __fmul_rn(z, z); }
        }
        zsql[tid] = np_pairwise32(sq);
    }
    __syncthreads();

    // ---- P9a: z fragment -> registers ----
    const int G    = (V + 63) >> 6;
    const int cp   = 16 / G;
    const int w    = tid >> 6;
    const int lane = tid & 63;
    const int g = w / cp, sub = w - g*cp;
    float zreg[32]; float myzsq = 0.f;
    if (g < G) {
        const int v  = g*64 + lane;
        const int vc = min(v, V - 1);
        if (pn == 16) {
            #pragma unroll
            for (int c = 0; c < 32; ++c) zreg[c] = frest[vc*33 + c];
        } else {
            #pragma unroll
            for (int c = 0; c < 32; ++c) zreg[c] = zh[c*VP + vc];
        }
        myzsq = zsql[vc];
    }
    __syncthreads();   // frest region free -> overlay

    // ---- P9b: scan chunk; d = fl(fl(zsq+esq) - fl(2*g)), g = sequential-k fma (BLAS) ----
    float best = INFINITY; int bidx = 0;
    if (g < G) {
        const int cszb  = (1024 + cp - 1) / cp;
        const int jb    = chunk*1024 + sub*cszb;
        const int count = min(cszb, 1024 - sub*cszb);
        const int jbase = __builtin_amdgcn_readfirstlane(jb);
        const float* __restrict__ ep = emb + (size_t)jbase*32;
        const float* __restrict__ sq = esq + jbase;
        for (int jj = 0; jj < count; ++jj) {
            float acc = 0.f;
            #pragma unroll
            for (int c = 0; c < 32; ++c) acc = __fmaf_rn(ep[jj*32 + c], zreg[c], acc);
            float d = __fsub_rn(__fadd_rn(myzsq, sq[jj]), __fmul_rn(2.0f, acc));
            if (d < best) { best = d; bidx = jbase + jj; }   // strict <: first-index ties
        }
    }
    psc_l[w*64 + lane] = best;
    pix_l[w*64 + lane] = bidx;
    __syncthreads();

    // ---- P10: intra-WG reduce (ascending sub => ascending j), write partials ----
    if (tid < V) {
        int gg = tid >> 6, ll = tid & 63;
        float bb = INFINITY; int bi = 0;
        for (int subi = 0; subi < cp; ++subi) {
            float sc = psc_l[(gg*cp + subi)*64 + ll];
            if (sc < bb) { bb = sc; bi = pix_l[(gg*cp + subi)*64 + ll]; }
        }
        psc[(size_t)((sIdx & 1)*64 + b)*1024 + chunk*256 + tid] = bb;
        pix[(size_t)((sIdx & 1)*64 + b)*1024 + chunk*256 + tid] = bi;
    }
}

__global__ __launch_bounds__(1024) void vq_final(
    const float* __restrict__ emb, const float* __restrict__ fhat,
    const float* __restrict__ psc, const int* __restrict__ pix,
    float* __restrict__ out)
{
    __shared__ int idx_arr[256];
    const int tid = threadIdx.x;
    const int b = blockIdx.x;
    if (tid < 256) {
        float best = INFINITY; int bi = 0;
        for (int ch = 0; ch < 4; ++ch) {
            float sc = psc[(size_t)(1*64 + b)*1024 + ch*256 + tid];  // scale 9 -> slot 1
            if (sc < best) { best = sc; bi = pix[(size_t)(1*64 + b)*1024 + ch*256 + tid]; }
        }
        idx_arr[tid] = bi;
    }
    __syncthreads();
    // out = transpose(f_hat + h9), BCHW coalesced; h9 = emb[idx] (last scale: no resize)
    for (int o = tid; o < 8192; o += 1024) {
        int c = o >> 8, yx = o & 255;
        out[b*8192 + o] = __fadd_rn(fhat[(size_t)b*8192 + yx*32 + c],
                                    emb[(size_t)idx_arr[yx]*32 + c]);
    }
}

extern "C" void kernel_launch(void* const* d_in, const int* in_sizes, int n_in,
                              void* d_out, int out_size, void* d_ws, size_t ws_size,
                              hipStream_t stream) {
    const float* f   = (const float*)d_in[0];
    const float* emb = (const float*)d_in[1];
    float* ws  = (float*)d_ws;
    float* out = (float*)d_out;
    float* esq   = ws + WS_ESQ;
    float* state = ws + WS_STATE;
    float* fhatp = ws + WS_FHAT;
    float* psc   = ws + WS_PSC;
    int*   pixp  = (int*)(ws + WS_PIX);
    static const int pns[10] = {1, 2, 3, 4, 5, 6, 8, 10, 13, 16};

    vq_prep<<<16, 256, 0, stream>>>(emb, esq);
    for (int s = 0; s < 10; ++s)
        vq_scale<<<256, 1024, 0, stream>>>(f, emb, esq, state, fhatp, psc, pixp,
                                           s, pns[s], s > 0 ? pns[s-1] : 0);
    vq_final<<<64, 1024, 0, stream>>>(emb, fhatp, psc, pixp, out);
}

// Round 4
// 611.477 us; speedup vs baseline: 1.1651x; 1.1651x over previous
//
#include <hip/hip_runtime.h>
#include <math.h>

// ws layout (floats):
//   esq   : [4096]
//   state : [2][64*8192]   ping-pong f_rest, [b][yx*32+c]
//   fhat  : [64*8192]      f_hat accumulator, [b][yx*32+c]
//   psc   : [2][64][4][256] float
//   pix   : [2][64][4][256] int
#define WS_ESQ   0
#define WS_STATE 4096
#define WS_FHAT  (4096 + 2*524288)
#define WS_PSC   (4096 + 3*524288)
#define WS_PIX   (4096 + 3*524288 + 2*65536)

__device__ __forceinline__ float4 v4add(float4 a, float4 b) {
    return make_float4(__fadd_rn(a.x,b.x), __fadd_rn(a.y,b.y),
                       __fadd_rn(a.z,b.z), __fadd_rn(a.w,b.w));
}
__device__ __forceinline__ float4 v4sq(float4 a) {
    return make_float4(__fmul_rn(a.x,a.x), __fmul_rn(a.y,a.y),
                       __fmul_rn(a.z,a.z), __fmul_rn(a.w,a.w));
}
// numpy pairwise sum of 32 pre-rounded squares held in 8 float4s
// (q0={sq0..3}, q1={sq4..7}, q2={sq8..11}, ..., q7={sq28..31})
// r[t] = ((sq[t]+sq[t+8])+sq[t+16])+sq[t+24]; l=(r0+r1)+(r2+r3); h=(r4+r5)+(r6+r7)
__device__ __forceinline__ float np_pw32(float4 q0, float4 q1, float4 q2, float4 q3,
                                         float4 q4, float4 q5, float4 q6, float4 q7) {
    float4 rA = v4add(v4add(v4add(q0, q2), q4), q6);   // r[0..3]
    float4 rB = v4add(v4add(v4add(q1, q3), q5), q7);   // r[4..7]
    float l = __fadd_rn(__fadd_rn(rA.x, rA.y), __fadd_rn(rA.z, rA.w));
    float h = __fadd_rn(__fadd_rn(rB.x, rB.y), __fadd_rn(rB.z, rB.w));
    return __fadd_rn(l, h);
}

__global__ void vq_prep(const float* __restrict__ emb, float* __restrict__ esq) {
    int j = blockIdx.x * 256 + threadIdx.x;
    if (j < 4096) {
        const float4* e4 = (const float4*)(emb + (size_t)j*32);
        float4 q0 = v4sq(e4[0]), q1 = v4sq(e4[1]), q2 = v4sq(e4[2]), q3 = v4sq(e4[3]);
        float4 q4 = v4sq(e4[4]), q5 = v4sq(e4[5]), q6 = v4sq(e4[6]), q7 = v4sq(e4[7]);
        esq[j] = np_pw32(q0,q1,q2,q3,q4,q5,q6,q7);
    }
}

__device__ __forceinline__ double keys64(double x) {
    // jax keys cubic (a=-0.5)
    if (x < 1.0)      return ((1.5*x - 2.5)*x)*x + 1.0;
    else if (x < 2.0) return ((-0.5*x + 2.5)*x - 4.0)*x + 2.0;
    return 0.0;
}

#define DOT4(E, OFF, Z) \
    acc = __fmaf_rn(E[OFF+0], Z.x, acc); acc = __fmaf_rn(E[OFF+1], Z.y, acc); \
    acc = __fmaf_rn(E[OFF+2], Z.z, acc); acc = __fmaf_rn(E[OFF+3], Z.w, acc);

__global__ __launch_bounds__(1024) void vq_scale(
    const float* __restrict__ f, const float* __restrict__ emb,
    const float* __restrict__ esq, float* __restrict__ state,
    float* __restrict__ fhat, float* __restrict__ psc, int* __restrict__ pix,
    int sIdx, int pn, int pnPrev)
{
    __shared__ __align__(16) float frest[256*33]; // [yx*33+c]; overlaid by psc_l/pix_l in scan
    __shared__ float zh[5440];        // union: h [v*32+c] (P3-P5) / zT [c*VP+v] (P7-P9)
    __shared__ int   idx_arr[256];
    __shared__ float U[16*16];        // bicubic weights [out][in], fp64->fp32 like jax

    float* psc_l = frest;                 // scan-phase overlay: 16*64 floats
    int*   pix_l = (int*)(frest + 1024);  // 16*64 ints

    const int tid   = threadIdx.x;
    const int b     = blockIdx.x >> 2;
    const int chunk = blockIdx.x & 3;

    // ---- P1: load f_rest into LDS ----
    if (sIdx == 0) {
        for (int o = tid; o < 8192; o += 1024) {           // o = c*256+yx (coalesced in f)
            int c = o >> 8, yx = o & 255;
            frest[yx*33 + c] = f[b*8192 + o];
        }
    } else {
        const float* st = state + (size_t)(sIdx & 1)*524288 + b*8192;
        for (int o = tid; o < 8192; o += 1024)
            frest[(o >> 5)*33 + (o & 31)] = st[o];
    }
    __syncthreads();

    if (sIdx > 0) {
        const int Vp = pnPrev * pnPrev;
        const int ps = (sIdx - 1) & 1;
        // ---- P2: combine prev-scale partial argmins (ascending chunk = ascending j) ----
        if (tid < Vp) {
            float best = INFINITY; int bi = 0;
            for (int ch = 0; ch < 4; ++ch) {
                float sc = psc[(size_t)(ps*64 + b)*1024 + ch*256 + tid];
                if (sc < best) { best = sc; bi = pix[(size_t)(ps*64 + b)*1024 + ch*256 + tid]; }
            }
            idx_arr[tid] = bi;
        }
        __syncthreads();
        // ---- P3: gather h = emb[idx] ----
        for (int t = tid; t < Vp*32; t += 1024)
            zh[t] = emb[(size_t)idx_arr[t >> 5]*32 + (t & 31)];
        // ---- P4: bicubic weights in fp64 exactly like jax, cast fp32 after normalize ----
        if (tid < 16) {
            double scl = 16.0 / (double)pnPrev;
            double inv = 1.0 / scl;
            double s = ((double)tid + 0.5) * inv - 0.5;
            double w64[16]; double tot = 0.0;
            for (int q = 0; q < pnPrev; ++q) {
                double wv = keys64(fabs(s - (double)q));
                w64[q] = wv; tot += wv;
            }
            for (int q = 0; q < pnPrev; ++q) U[tid*16 + q] = (float)(w64[q] / tot);
        }
        __syncthreads();
        // ---- P5: upsample-apply, windowed to nonzero taps (zero terms are exact
        //          identities in the einsum sum => bit-identical to full loop).
        //          term = fl(fl(h*wy)*wx), p outer asc, q inner asc, fl adds. ----
        float* stn = state + (size_t)((sIdx + 1) & 1)*524288 + b*8192;
        float* fh  = fhat + (size_t)b*8192;
        const double inv = 1.0 / (16.0 / (double)pnPrev);
        for (int o = tid; o < 8192; o += 1024) {
            int c = o & 31, yx = o >> 5, y = yx >> 4, x = yx & 15;
            double sy = ((double)y + 0.5) * inv - 0.5;
            double sx = ((double)x + 0.5) * inv - 0.5;
            int p0 = (int)floor(sy) - 1, q0 = (int)floor(sx) - 1;
            int pa = max(0, p0), pb = min(pnPrev - 1, p0 + 3);
            int qa = max(0, q0), qb = min(pnPrev - 1, q0 + 3);
            float acc = 0.f;
            for (int p = pa; p <= pb; ++p) {
                float wy = U[y*16 + p];
                for (int q = qa; q <= qb; ++q) {
                    float t0 = __fmul_rn(zh[(p*pnPrev + q)*32 + c], wy);
                    t0 = __fmul_rn(t0, U[x*16 + q]);
                    acc = __fadd_rn(acc, t0);
                }
            }
            float fr = __fsub_rn(frest[yx*33 + c], acc);
            frest[yx*33 + c] = fr;
            if (chunk == 0) {
                stn[o] = fr;
                fh[o] = (sIdx == 1) ? acc : __fadd_rn(fh[o], acc);  // f_hat chain
            }
        }
        __syncthreads();
    } else {
        // s==0: persist unmodified f_rest to next slot
        float* stn = state + (size_t)1*524288 + b*8192;
        if (chunk == 0)
            for (int o = tid; o < 8192; o += 1024)
                stn[o] = frest[(o >> 5)*33 + (o & 31)];
    }

    // ---- P7: area pooling, np einsum order: term=fl(coef*f) added h-outer/w-inner ----
    const int V  = pn * pn;
    const int VP = V | 1;
    if (pn < 16) {
        for (int t = tid; t < V*32; t += 1024) {
            int v = t >> 5, c = t & 31;
            int p = v / pn, q = v - p*pn;
            int sh = (p*16)/pn, eh = ((p+1)*16 + pn - 1)/pn;
            int sw = (q*16)/pn, ew = ((q+1)*16 + pn - 1)/pn;
            float Mh = (float)(1.0/(double)(eh - sh));
            float Mw = (float)(1.0/(double)(ew - sw));
            float coef = __fmul_rn(Mh, Mw);
            float acc = 0.f;
            for (int hh = sh; hh < eh; ++hh)
                for (int wy = sw; wy < ew; ++wy)
                    acc = __fadd_rn(acc, __fmul_rn(coef, frest[(hh*16 + wy)*33 + c]));
            zh[c*VP + v] = acc;
        }
    }
    __syncthreads();

    // ---- P9a: z fragment -> 8 float4 registers (no indexable array => no scratch) ----
    const int G    = (V + 63) >> 6;
    const int cp   = 16 / G;              // 16,16,16,16,16,16,16,8,5,4
    const int w    = tid >> 6;
    const int lane = tid & 63;
    const int g = w / cp, sub = w - g*cp;
    float4 z0 = {0,0,0,0}, z1 = {0,0,0,0}, z2 = {0,0,0,0}, z3 = {0,0,0,0};
    float4 z4 = {0,0,0,0}, z5 = {0,0,0,0}, z6 = {0,0,0,0}, z7 = {0,0,0,0};
    float myzsq = 0.f;
    if (g < G) {
        const int vc = min(g*64 + lane, V - 1);
        if (pn == 16) {
            const float* zp = &frest[vc*33];
            z0 = make_float4(zp[0],zp[1],zp[2],zp[3]);
            z1 = make_float4(zp[4],zp[5],zp[6],zp[7]);
            z2 = make_float4(zp[8],zp[9],zp[10],zp[11]);
            z3 = make_float4(zp[12],zp[13],zp[14],zp[15]);
            z4 = make_float4(zp[16],zp[17],zp[18],zp[19]);
            z5 = make_float4(zp[20],zp[21],zp[22],zp[23]);
            z6 = make_float4(zp[24],zp[25],zp[26],zp[27]);
            z7 = make_float4(zp[28],zp[29],zp[30],zp[31]);
        } else {
            const float* zp = &zh[vc];
            z0 = make_float4(zp[0*VP],zp[1*VP],zp[2*VP],zp[3*VP]);
            z1 = make_float4(zp[4*VP],zp[5*VP],zp[6*VP],zp[7*VP]);
            z2 = make_float4(zp[8*VP],zp[9*VP],zp[10*VP],zp[11*VP]);
            z3 = make_float4(zp[12*VP],zp[13*VP],zp[14*VP],zp[15*VP]);
            z4 = make_float4(zp[16*VP],zp[17*VP],zp[18*VP],zp[19*VP]);
            z5 = make_float4(zp[20*VP],zp[21*VP],zp[22*VP],zp[23*VP]);
            z6 = make_float4(zp[24*VP],zp[25*VP],zp[26*VP],zp[27*VP]);
            z7 = make_float4(zp[28*VP],zp[29*VP],zp[30*VP],zp[31*VP]);
        }
        myzsq = np_pw32(v4sq(z0),v4sq(z1),v4sq(z2),v4sq(z3),
                        v4sq(z4),v4sq(z5),v4sq(z6),v4sq(z7));
    }
    __syncthreads();   // frest region free -> overlay by psc_l/pix_l

    // ---- P9b: scan chunk; d = fl(fl(zsq+esq) - fl(2*g)), g = sequential-k fma (BLAS) ----
    float best = INFINITY; int bidx = 0;
    if (g < G) {
        const int cszb  = (1024 + cp - 1) / cp;
        const int jb    = chunk*1024 + sub*cszb;
        const int count = min(cszb, 1024 - sub*cszb);
        const int jbase = __builtin_amdgcn_readfirstlane(jb);
        const float* __restrict__ ep = emb + (size_t)jbase*32;
        const float* __restrict__ sq = esq + jbase;
        #pragma unroll 2
        for (int jj = 0; jj < count; ++jj) {
            const float* e = ep + jj*32;
            float acc = 0.f;
            DOT4(e, 0,  z0) DOT4(e, 4,  z1) DOT4(e, 8,  z2) DOT4(e, 12, z3)
            DOT4(e, 16, z4) DOT4(e, 20, z5) DOT4(e, 24, z6) DOT4(e, 28, z7)
            float d = __fsub_rn(__fadd_rn(myzsq, sq[jj]), __fmul_rn(2.0f, acc));
            if (d < best) { best = d; bidx = jbase + jj; }   // strict <: first-index ties
        }
    }
    psc_l[w*64 + lane] = best;
    pix_l[w*64 + lane] = bidx;
    __syncthreads();

    // ---- P10: intra-WG reduce (ascending sub => ascending j), write partials ----
    if (tid < V) {
        int gg = tid >> 6, ll = tid & 63;
        float bb = INFINITY; int bi = 0;
        for (int subi = 0; subi < cp; ++subi) {
            float sc = psc_l[(gg*cp + subi)*64 + ll];
            if (sc < bb) { bb = sc; bi = pix_l[(gg*cp + subi)*64 + ll]; }
        }
        psc[(size_t)((sIdx & 1)*64 + b)*1024 + chunk*256 + tid] = bb;
        pix[(size_t)((sIdx & 1)*64 + b)*1024 + chunk*256 + tid] = bi;
    }
}

__global__ __launch_bounds__(1024) void vq_final(
    const float* __restrict__ emb, const float* __restrict__ fhat,
    const float* __restrict__ psc, const int* __restrict__ pix,
    float* __restrict__ out)
{
    __shared__ int idx_arr[256];
    const int tid = threadIdx.x;
    const int b = blockIdx.x;
    if (tid < 256) {
        float best = INFINITY; int bi = 0;
        for (int ch = 0; ch < 4; ++ch) {
            float sc = psc[(size_t)(1*64 + b)*1024 + ch*256 + tid];  // scale 9 -> slot 1
            if (sc < best) { best = sc; bi = pix[(size_t)(1*64 + b)*1024 + ch*256 + tid]; }
        }
        idx_arr[tid] = bi;
    }
    __syncthreads();
    // out = transpose(f_hat + h9), BCHW coalesced; h9 = emb[idx] (last scale: no resize)
    for (int o = tid; o < 8192; o += 1024) {
        int c = o >> 8, yx = o & 255;
        out[b*8192 + o] = __fadd_rn(fhat[(size_t)b*8192 + yx*32 + c],
                                    emb[(size_t)idx_arr[yx]*32 + c]);
    }
}

extern "C" void kernel_launch(void* const* d_in, const int* in_sizes, int n_in,
                              void* d_out, int out_size, void* d_ws, size_t ws_size,
                              hipStream_t stream) {
    const float* f   = (const float*)d_in[0];
    const float* emb = (const float*)d_in[1];
    float* ws  = (float*)d_ws;
    float* out = (float*)d_out;
    float* esq   = ws + WS_ESQ;
    float* state = ws + WS_STATE;
    float* fhatp = ws + WS_FHAT;
    float* psc   = ws + WS_PSC;
    int*   pixp  = (int*)(ws + WS_PIX);
    static const int pns[10] = {1, 2, 3, 4, 5, 6, 8, 10, 13, 16};

    vq_prep<<<16, 256, 0, stream>>>(emb, esq);
    for (int s = 0; s < 10; ++s)
        vq_scale<<<256, 1024, 0, stream>>>(f, emb, esq, state, fhatp, psc, pixp,
                                           s, pns[s], s > 0 ? pns[s-1] : 0);
    vq_final<<<64, 1024, 0, stream>>>(emb, fhatp, psc, pixp, out);
}